// Round 7
// baseline (388.424 us; speedup 1.0000x reference)
//
#include <hip/hip_runtime.h>
#include <hip/hip_bf16.h>
#include <math.h>

#define N_CLS 1000
#define FEAT  1024
#define BATCH 32768
#define NBLK  256
#define CHUNK 128
#define LPITCH 72

typedef short short8 __attribute__((ext_vector_type(8)));
typedef float f32x4  __attribute__((ext_vector_type(4)));

__device__ __forceinline__ unsigned short f2bf(float x) {
    union { __hip_bfloat16 h; unsigned short u; } cv;
    cv.h = __float2bfloat16(x);
    return cv.u;
}
__device__ __forceinline__ float bf2f(unsigned short u) {
    union { __hip_bfloat16 h; unsigned short u; } cv;
    cv.u = u;
    return __bfloat162float(cv.h);
}

// grid-wide spin barrier: all NBLK blocks co-resident (grid == 256 == #CUs).
// release: threadfence + ACQ_REL add; acquire: ACQUIRE load observing count==NBLK.
__device__ __forceinline__ void gbar(unsigned* ctr) {
    __syncthreads();
    if (threadIdx.x == 0) {
        __threadfence();
        __hip_atomic_fetch_add(ctr, 1u, __ATOMIC_ACQ_REL, __HIP_MEMORY_SCOPE_AGENT);
        while (__hip_atomic_load(ctr, __ATOMIC_ACQUIRE, __HIP_MEMORY_SCOPE_AGENT) < NBLK)
            __builtin_amdgcn_s_sleep(2);
    }
    __syncthreads();
}

__device__ __forceinline__ float4 ema4(float4 p, float4 f) {
    p.x = fmaf(0.95f, p.x, 0.05f * f.x);
    p.y = fmaf(0.95f, p.y, 0.05f * f.y);
    p.z = fmaf(0.95f, p.z, 0.05f * f.z);
    p.w = fmaf(0.95f, p.w, 0.05f * f.w);
    return p;
}
__device__ __forceinline__ float dot4(float4 a) {
    return a.x * a.x + a.y * a.y + a.z * a.z + a.w * a.w;
}
__device__ __forceinline__ float4 scale4(float4 a, float s) {
    a.x *= s; a.y *= s; a.z *= s; a.w *= s; return a;
}

__device__ __forceinline__ void ema_step(float4& p0, float4& p1, float4& p2, float4& p3,
                                         float4& x0, float4& x1, float4& x2, float4& x3,
                                         const float* __restrict__ features, int iN, int lane) {
    p0 = ema4(p0, x0); p1 = ema4(p1, x1); p2 = ema4(p2, x2); p3 = ema4(p3, x3);
    const float4* f = (const float4*)(features + (size_t)iN * FEAT);   // prefetch next
    x0 = f[lane]; x1 = f[lane + 64]; x2 = f[lane + 128]; x3 = f[lane + 192];
    float ss = dot4(p0) + dot4(p1) + dot4(p2) + dot4(p3);
    #pragma unroll
    for (int o = 32; o; o >>= 1) ss += __shfl_xor(ss, o, 64);
    const float inv = 1.0f / fmaxf(sqrtf(ss), 1e-12f);
    p0 = scale4(p0, inv); p1 = scale4(p1, inv); p2 = scale4(p2, inv); p3 = scale4(p3, inv);
}

__device__ __forceinline__ void write_hl(unsigned short* __restrict__ H,
                                         unsigned short* __restrict__ L,
                                         size_t off, float4 v) {
    ushort4 hi, lo;
    hi.x = f2bf(v.x); lo.x = f2bf(v.x - bf2f(hi.x));
    hi.y = f2bf(v.y); lo.y = f2bf(v.y - bf2f(hi.y));
    hi.z = f2bf(v.z); lo.z = f2bf(v.z - bf2f(hi.z));
    hi.w = f2bf(v.w); lo.w = f2bf(v.w - bf2f(hi.w));
    *(ushort4*)(H + off) = hi;
    *(ushort4*)(L + off) = lo;
}

__global__ __launch_bounds__(256, 1) void mono_kernel(
        const float* __restrict__ features, const float* __restrict__ prototypes,
        const int* __restrict__ labels,
        unsigned* __restrict__ hist, unsigned* __restrict__ base,
        unsigned* __restrict__ total, int* __restrict__ sorted_idx,
        float* __restrict__ S, unsigned* __restrict__ ctr,
        unsigned short* __restrict__ Hg, unsigned short* __restrict__ Lg,
        float* __restrict__ out) {
    __shared__ __align__(16) char smem[4 * 64 * LPITCH * 2];   // 36864 B, phase-aliased
    const int t = threadIdx.x, b = blockIdx.x;

    // ---------- P1: histogram (transposed hist[l][b]), zero S ----------
    {
        unsigned* cnt = (unsigned*)smem;
        for (int i = t; i < N_CLS; i += 256) cnt[i] = 0;
        if (b == 0) for (int i = t; i < N_CLS; i += 256) S[i] = 0.0f;
        __syncthreads();
        if (t < CHUNK) atomicAdd(&cnt[labels[b * CHUNK + t]], 1u);
        __syncthreads();
        for (int i = t; i < N_CLS; i += 256) hist[(size_t)i * NBLK + b] = cnt[i];
    }
    gbar(&ctr[0]);

    // ---------- P2a: per-label exclusive prefix over the 256 chunks ----------
    if (b < 250) {
        const int l = b * 4 + (t >> 6);
        const int lane = t & 63;
        unsigned* hrow = hist + (size_t)l * NBLK + lane * 4;
        unsigned e0 = hrow[0], e1 = hrow[1], e2 = hrow[2], e3 = hrow[3];
        unsigned s = e0 + e1 + e2 + e3;
        unsigned x = s;
        #pragma unroll
        for (int off = 1; off < 64; off <<= 1) {
            unsigned u = __shfl_up(x, off, 64);
            if (lane >= off) x += u;
        }
        unsigned run = x - s;                      // exclusive over lanes
        hrow[0] = run; run += e0;
        hrow[1] = run; run += e1;
        hrow[2] = run; run += e2;
        hrow[3] = run;
        if (lane == 63) total[l] = x;
    }
    gbar(&ctr[1]);

    // ---------- P2b: exclusive scan of total[1000] -> base (block 0 only) ----------
    if (b == 0) {
        unsigned* sc = (unsigned*)smem;
        unsigned v[4], s = 0;
        #pragma unroll
        for (int j = 0; j < 4; ++j) {
            const int i = t * 4 + j;
            v[j] = (i < N_CLS) ? total[i] : 0u;
            s += v[j];
        }
        sc[t] = s;
        __syncthreads();
        for (int off = 1; off < 256; off <<= 1) {
            unsigned u = (t >= off) ? sc[t - off] : 0u;
            __syncthreads();
            sc[t] += u;
            __syncthreads();
        }
        unsigned acc = sc[t] - s;
        #pragma unroll
        for (int j = 0; j < 4; ++j) {
            const int i = t * 4 + j;
            if (i < N_CLS) base[i] = acc;
            acc += v[j];
        }
    }
    gbar(&ctr[2]);

    // ---------- P3: stable scatter ----------
    {
        int* lbl      = (int*)smem;                  // 128 ints
        unsigned* c   = (unsigned*)(smem + 512);     // 1000 u32
        for (int i = t; i < N_CLS; i += 256) c[i] = 0;
        __syncthreads();
        int l = 0, i = 0;
        if (t < CHUNK) {
            i = b * CHUNK + t;
            l = labels[i];
            lbl[t] = l;
            atomicAdd(&c[l], 1u);
        }
        __syncthreads();
        if (t < CHUNK) {
            int rank = 0;
            if (c[l] > 1) {
                for (int j = 0; j < t; ++j) rank += (lbl[j] == l);
            }
            sorted_idx[base[l] + hist[(size_t)l * NBLK + b] + (unsigned)rank] = i;
        }
    }
    gbar(&ctr[3]);

    // ---------- P4: EMA chains (wave per label), 3-buffer rotating prefetch ----------
    if (b < 250) {
        const int w    = b * 4 + (t >> 6);
        const int lane = t & 63;
        const float4* pr = (const float4*)(prototypes + (size_t)w * FEAT);
        float4 p0 = pr[lane], p1 = pr[lane + 64], p2 = pr[lane + 128], p3 = pr[lane + 192];

        const int cnt = (int)total[w];
        const int bs  = (int)base[w];
        int myidx = (lane < cnt) ? sorted_idx[bs + lane] : 0;

        #define GETIDX(K) (((K) < cnt) ? (((K) < 64) ? __shfl(myidx, (K), 64) : sorted_idx[bs + (K)]) : 0)

        const int iA = GETIDX(0), iB = GETIDX(1), iC = GETIDX(2);
        const float4* fA = (const float4*)(features + (size_t)iA * FEAT);
        float4 a0 = fA[lane], a1 = fA[lane + 64], a2 = fA[lane + 128], a3 = fA[lane + 192];
        const float4* fB = (const float4*)(features + (size_t)iB * FEAT);
        float4 b0 = fB[lane], b1 = fB[lane + 64], b2 = fB[lane + 128], b3 = fB[lane + 192];
        const float4* fC = (const float4*)(features + (size_t)iC * FEAT);
        float4 c0 = fC[lane], c1 = fC[lane + 64], c2 = fC[lane + 128], c3 = fC[lane + 192];

        int k = 0;
        while (k + 3 <= cnt) {
            ema_step(p0,p1,p2,p3, a0,a1,a2,a3, features, GETIDX(k + 3), lane); ++k;
            ema_step(p0,p1,p2,p3, b0,b1,b2,b3, features, GETIDX(k + 3), lane); ++k;
            ema_step(p0,p1,p2,p3, c0,c1,c2,c3, features, GETIDX(k + 3), lane); ++k;
        }
        if (k < cnt) { ema_step(p0,p1,p2,p3, a0,a1,a2,a3, features, 0, lane); ++k; }
        if (k < cnt) { ema_step(p0,p1,p2,p3, b0,b1,b2,b3, features, 0, lane); ++k; }
        #undef GETIDX

        const size_t rb = (size_t)w * FEAT;
        write_hl(Hg, Lg, rb +       4 * lane, p0);
        write_hl(Hg, Lg, rb + 256 + 4 * lane, p1);
        write_hl(Hg, Lg, rb + 512 + 4 * lane, p2);
        write_hl(Hg, Lg, rb + 768 + 4 * lane, p3);
    }
    gbar(&ctr[4]);

    // ---------- P5: MFMA gram C = H·H^T + L·H^T + H·L^T, exp row-sums + fused loss ----------
    {
        short* Hms = (short*)smem;
        short* Lms = Hms + 64 * LPITCH;
        short* Hns = Lms + 64 * LPITCH;
        short* Lns = Hns + 64 * LPITCH;
        const int l = t & 63, wid = t >> 6;
        const int wr = wid >> 1, wc = wid & 1;
        const int m0 = (b >> 4) * 64, n0 = (b & 15) * 64;
        const int lg = l >> 4, lc = l & 15;

        const short* Hp = (const short*)Hg;
        const short* Lp = (const short*)Lg;

        f32x4 acc[2][2] = {};

        const int r0 = t >> 3,          c0 = t & 7;
        const int r1 = (t + 256) >> 3,  c1 = t & 7;

        for (int k0 = 0; k0 < FEAT; k0 += 64) {
            short8 hm0 = *(const short8*)(Hp + (size_t)(m0 + r0) * FEAT + k0 + c0 * 8);
            short8 hm1 = *(const short8*)(Hp + (size_t)(m0 + r1) * FEAT + k0 + c1 * 8);
            short8 lm0 = *(const short8*)(Lp + (size_t)(m0 + r0) * FEAT + k0 + c0 * 8);
            short8 lm1 = *(const short8*)(Lp + (size_t)(m0 + r1) * FEAT + k0 + c1 * 8);
            short8 hn0 = *(const short8*)(Hp + (size_t)(n0 + r0) * FEAT + k0 + c0 * 8);
            short8 hn1 = *(const short8*)(Hp + (size_t)(n0 + r1) * FEAT + k0 + c1 * 8);
            short8 ln0 = *(const short8*)(Lp + (size_t)(n0 + r0) * FEAT + k0 + c0 * 8);
            short8 ln1 = *(const short8*)(Lp + (size_t)(n0 + r1) * FEAT + k0 + c1 * 8);
            __syncthreads();
            *(short8*)(Hms + r0 * LPITCH + c0 * 8) = hm0;
            *(short8*)(Hms + r1 * LPITCH + c1 * 8) = hm1;
            *(short8*)(Lms + r0 * LPITCH + c0 * 8) = lm0;
            *(short8*)(Lms + r1 * LPITCH + c1 * 8) = lm1;
            *(short8*)(Hns + r0 * LPITCH + c0 * 8) = hn0;
            *(short8*)(Hns + r1 * LPITCH + c1 * 8) = hn1;
            *(short8*)(Lns + r0 * LPITCH + c0 * 8) = ln0;
            *(short8*)(Lns + r1 * LPITCH + c1 * 8) = ln1;
            __syncthreads();
            #pragma unroll
            for (int kk = 0; kk < 2; ++kk) {
                short8 ah[2], al[2], bh[2], bl[2];
                #pragma unroll
                for (int mi = 0; mi < 2; ++mi) {
                    ah[mi] = *(const short8*)(Hms + (wr * 32 + mi * 16 + lc) * LPITCH + kk * 32 + lg * 8);
                    al[mi] = *(const short8*)(Lms + (wr * 32 + mi * 16 + lc) * LPITCH + kk * 32 + lg * 8);
                }
                #pragma unroll
                for (int ni = 0; ni < 2; ++ni) {
                    bh[ni] = *(const short8*)(Hns + (wc * 32 + ni * 16 + lc) * LPITCH + kk * 32 + lg * 8);
                    bl[ni] = *(const short8*)(Lns + (wc * 32 + ni * 16 + lc) * LPITCH + kk * 32 + lg * 8);
                }
                #pragma unroll
                for (int mi = 0; mi < 2; ++mi)
                    #pragma unroll
                    for (int ni = 0; ni < 2; ++ni) {
                        acc[mi][ni] = __builtin_amdgcn_mfma_f32_16x16x32_bf16(ah[mi], bh[ni], acc[mi][ni], 0, 0, 0);
                        acc[mi][ni] = __builtin_amdgcn_mfma_f32_16x16x32_bf16(al[mi], bh[ni], acc[mi][ni], 0, 0, 0);
                        acc[mi][ni] = __builtin_amdgcn_mfma_f32_16x16x32_bf16(ah[mi], bl[ni], acc[mi][ni], 0, 0, 0);
                    }
            }
        }

        #pragma unroll
        for (int mi = 0; mi < 2; ++mi) {
            #pragma unroll
            for (int j = 0; j < 4; ++j) {
                const int gr = m0 + wr * 32 + mi * 16 + lg * 4 + j;
                float s = 0.f;
                #pragma unroll
                for (int ni = 0; ni < 2; ++ni) {
                    const int gc = n0 + wc * 32 + ni * 16 + lc;
                    if (gr < N_CLS && gc < N_CLS && gr != gc) s += expf(acc[mi][ni][j] * 10.0f);
                }
                #pragma unroll
                for (int m = 1; m < 16; m <<= 1) s += __shfl_xor(s, m, 64);
                if (lc == 0 && gr < N_CLS) atomicAdd(&S[gr], s);
            }
        }

        // last block reduces S -> loss
        __threadfence();
        __shared__ int amlast;
        if (t == 0) {
            unsigned old = __hip_atomic_fetch_add(&ctr[5], 1u, __ATOMIC_ACQ_REL, __HIP_MEMORY_SCOPE_AGENT);
            amlast = (old == NBLK - 1) ? 1 : 0;
        }
        __syncthreads();
        if (amlast) {
            float a = 0.f;
            for (int i = t; i < N_CLS; i += 256) {
                float sv = __hip_atomic_load(&S[i], __ATOMIC_RELAXED, __HIP_MEMORY_SCOPE_AGENT);
                a += logf(sv);
            }
            #pragma unroll
            for (int o = 32; o; o >>= 1) a += __shfl_xor(a, o, 64);
            __shared__ float red[4];
            if (l == 0) red[wid] = a;
            __syncthreads();
            if (t == 0) {
                float tot = red[0] + red[1] + red[2] + red[3];
                out[0] = tot / (float)N_CLS - logf(999.0f);   // TEMP/BASE_TEMP == 1.0
            }
        }
    }
}

extern "C" void kernel_launch(void* const* d_in, const int* in_sizes, int n_in,
                              void* d_out, int out_size, void* d_ws, size_t ws_size,
                              hipStream_t stream) {
    const float* features   = (const float*)d_in[0];
    const float* prototypes = (const float*)d_in[1];
    const int*   labels     = (const int*)d_in[2];
    float* out = (float*)d_out;

    char* ws = (char*)d_ws;
    unsigned*       hist   = (unsigned*)(ws);                  // 1000*256*4 = 1,024,000
    unsigned*       base   = (unsigned*)(ws + 0x100000);       // 4 KB
    unsigned*       total  = (unsigned*)(ws + 0x101000);       // 4 KB
    int*            sorted = (int*)     (ws + 0x102000);       // 131072
    float*          S      = (float*)   (ws + 0x122000);       // 4 KB
    unsigned*       ctr    = (unsigned*)(ws + 0x123000);       // 32 B: [0..4]=barriers, [5]=loss
    unsigned short* Hg     = (unsigned short*)(ws + 0x200000); // 2 MB
    unsigned short* Lg     = (unsigned short*)(ws + 0x400000); // 2 MB

    hipMemsetAsync(ctr, 0, 32, stream);
    mono_kernel<<<NBLK, 256, 0, stream>>>(features, prototypes, labels,
                                          hist, base, total, sorted,
                                          S, ctr, Hg, Lg, out);
}

// Round 8
// 276.362 us; speedup vs baseline: 1.4055x; 1.4055x over previous
//
#include <hip/hip_runtime.h>
#include <hip/hip_bf16.h>
#include <math.h>

#define N_CLS 1000
#define FEAT  1024
#define BATCH 32768
#define NBLK_H 128
#define CHUNK  256
#define LPITCH 72
#define GRAM_BLOCKS 256
#define SCAN_BLOCKS 250

typedef short short8 __attribute__((ext_vector_type(8)));
typedef float f32x4  __attribute__((ext_vector_type(4)));

__device__ __forceinline__ unsigned short f2bf(float x) {
    union { __hip_bfloat16 h; unsigned short u; } cv;
    cv.h = __float2bfloat16(x);
    return cv.u;
}
__device__ __forceinline__ float bf2f(unsigned short u) {
    union { __hip_bfloat16 h; unsigned short u; } cv;
    cv.u = u;
    return __bfloat162float(cv.h);
}

// ---------------- counting-sort: histogram (transposed hist[l][b]) + zero S/counters ----------------
__global__ __launch_bounds__(256) void hist_kernel(const int* __restrict__ labels,
                                                   unsigned* __restrict__ hist,
                                                   float* __restrict__ S,
                                                   unsigned* __restrict__ counter) {
    __shared__ unsigned cnt[N_CLS];
    const int t = threadIdx.x, b = blockIdx.x;
    if (b == 0) {
        for (int i = t; i < N_CLS; i += 256) S[i] = 0.0f;
        if (t == 0) { counter[0] = 0u; counter[1] = 0u; }
    }
    for (int i = t; i < N_CLS; i += 256) cnt[i] = 0;
    __syncthreads();
    atomicAdd(&cnt[labels[b * CHUNK + t]], 1u);
    __syncthreads();
    for (int i = t; i < N_CLS; i += 256) hist[(size_t)i * NBLK_H + b] = cnt[i];
}

// ---------------- fused scan: per-label prefix over 128 blocks, last block scans totals ----------------
__global__ __launch_bounds__(256) void scan_kernel(unsigned* __restrict__ hist,
                                                   unsigned* __restrict__ total,
                                                   unsigned* __restrict__ base,
                                                   unsigned* __restrict__ counter) {
    const int t    = threadIdx.x;
    const int l    = blockIdx.x * 4 + (t >> 6);
    const int lane = t & 63;
    unsigned v0 = hist[(size_t)l * NBLK_H + lane];
    unsigned v1 = hist[(size_t)l * NBLK_H + 64 + lane];
    unsigned x0 = v0, x1 = v1;
    #pragma unroll
    for (int off = 1; off < 64; off <<= 1) {
        unsigned u0 = __shfl_up(x0, off, 64);
        if (lane >= off) x0 += u0;
        unsigned u1 = __shfl_up(x1, off, 64);
        if (lane >= off) x1 += u1;
    }
    x1 += __shfl(x0, 63, 64);
    hist[(size_t)l * NBLK_H + lane]      = x0 - v0;   // exclusive prefix over blocks
    hist[(size_t)l * NBLK_H + 64 + lane] = x1 - v1;
    if (lane == 63) total[l] = x1;

    // last finishing block computes the exclusive scan of total[1000] -> base
    __syncthreads();
    __threadfence();
    __shared__ int amlast;
    if (t == 0) {
        unsigned old = __hip_atomic_fetch_add(&counter[1], 1u, __ATOMIC_ACQ_REL, __HIP_MEMORY_SCOPE_AGENT);
        amlast = (old == SCAN_BLOCKS - 1) ? 1 : 0;
    }
    __syncthreads();
    if (!amlast) return;

    unsigned v[4];
    unsigned s = 0;
    #pragma unroll
    for (int j = 0; j < 4; ++j) {
        const int i = t * 4 + j;
        v[j] = (i < N_CLS) ? __hip_atomic_load(&total[i], __ATOMIC_RELAXED, __HIP_MEMORY_SCOPE_AGENT) : 0u;
        s += v[j];
    }
    __shared__ unsigned sc[256];
    sc[t] = s;
    __syncthreads();
    for (int off = 1; off < 256; off <<= 1) {
        unsigned u = (t >= off) ? sc[t - off] : 0u;
        __syncthreads();
        sc[t] += u;
        __syncthreads();
    }
    unsigned acc = sc[t] - s;                          // exclusive over thread sums
    #pragma unroll
    for (int j = 0; j < 4; ++j) {
        const int i = t * 4 + j;
        if (i < N_CLS) base[i] = acc;
        acc += v[j];
    }
}

// ---------------- counting-sort: stable scatter ----------------
__global__ __launch_bounds__(256) void scatter_kernel(const int* __restrict__ labels,
                                                      const unsigned* __restrict__ hist,
                                                      const unsigned* __restrict__ base,
                                                      int* __restrict__ sorted_idx) {
    __shared__ int lbl[CHUNK];
    __shared__ unsigned c[N_CLS];
    const int t = threadIdx.x, b = blockIdx.x;
    for (int i = t; i < N_CLS; i += 256) c[i] = 0;
    __syncthreads();
    const int i = b * CHUNK + t;
    const int l = labels[i];
    lbl[t] = l;
    atomicAdd(&c[l], 1u);
    __syncthreads();
    int rank = 0;
    if (c[l] > 1) {                       // only duplicated-in-block labels need ranking
        for (int j = 0; j < t; ++j) rank += (lbl[j] == l);
    }
    sorted_idx[base[l] + hist[(size_t)l * NBLK_H + b] + (unsigned)rank] = i;
}

// ---------------- EMA chains: DPP wave-reduce, 6-buffer rotating prefetch ----------------
__device__ __forceinline__ float4 ema4(float4 p, float4 f) {
    p.x = fmaf(0.95f, p.x, 0.05f * f.x);
    p.y = fmaf(0.95f, p.y, 0.05f * f.y);
    p.z = fmaf(0.95f, p.z, 0.05f * f.z);
    p.w = fmaf(0.95f, p.w, 0.05f * f.w);
    return p;
}
__device__ __forceinline__ float dot4(float4 a) {
    return a.x * a.x + a.y * a.y + a.z * a.z + a.w * a.w;
}
__device__ __forceinline__ float4 scale4(float4 a, float s) {
    a.x *= s; a.y *= s; a.z *= s; a.w *= s; return a;
}

// 64-lane sum via DPP (VALU-only; LLVM atomic-optimizer pattern), result uniform
__device__ __forceinline__ float wave_sum64(float x) {
    float s = x;
    s += __int_as_float(__builtin_amdgcn_update_dpp(0, __float_as_int(s), 0x111, 0xF, 0xF, true)); // row_shr:1
    s += __int_as_float(__builtin_amdgcn_update_dpp(0, __float_as_int(s), 0x112, 0xF, 0xF, true)); // row_shr:2
    s += __int_as_float(__builtin_amdgcn_update_dpp(0, __float_as_int(s), 0x114, 0xF, 0xF, true)); // row_shr:4
    s += __int_as_float(__builtin_amdgcn_update_dpp(0, __float_as_int(s), 0x118, 0xF, 0xF, true)); // row_shr:8
    s += __int_as_float(__builtin_amdgcn_update_dpp(0, __float_as_int(s), 0x142, 0xF, 0xF, true)); // row_bcast:15
    s += __int_as_float(__builtin_amdgcn_update_dpp(0, __float_as_int(s), 0x143, 0xF, 0xF, true)); // row_bcast:31
    return __int_as_float(__builtin_amdgcn_readlane(__float_as_int(s), 63));
}

// consume xc (row k), then prefetch row iN into the same buffer (6-deep rotation)
__device__ __forceinline__ void ema_step(float4& p0, float4& p1, float4& p2, float4& p3,
                                         float4& x0, float4& x1, float4& x2, float4& x3,
                                         const float* __restrict__ features, int iN, int lane) {
    p0 = ema4(p0, x0); p1 = ema4(p1, x1); p2 = ema4(p2, x2); p3 = ema4(p3, x3);
    const float4* f = (const float4*)(features + (size_t)iN * FEAT);
    x0 = f[lane]; x1 = f[lane + 64]; x2 = f[lane + 128]; x3 = f[lane + 192];
    const float ss = wave_sum64(dot4(p0) + dot4(p1) + dot4(p2) + dot4(p3));
    const float inv = 1.0f / fmaxf(sqrtf(ss), 1e-12f);
    p0 = scale4(p0, inv); p1 = scale4(p1, inv); p2 = scale4(p2, inv); p3 = scale4(p3, inv);
}

__device__ __forceinline__ void write_hl(unsigned short* __restrict__ H,
                                         unsigned short* __restrict__ L,
                                         size_t off, float4 v) {
    ushort4 hi, lo;
    hi.x = f2bf(v.x); lo.x = f2bf(v.x - bf2f(hi.x));
    hi.y = f2bf(v.y); lo.y = f2bf(v.y - bf2f(hi.y));
    hi.z = f2bf(v.z); lo.z = f2bf(v.z - bf2f(hi.z));
    hi.w = f2bf(v.w); lo.w = f2bf(v.w - bf2f(hi.w));
    *(ushort4*)(H + off) = hi;
    *(ushort4*)(L + off) = lo;
}

__global__ __launch_bounds__(256) void ema_kernel(const float* __restrict__ features,
                                                  const float* __restrict__ prototypes,
                                                  const int* __restrict__ sorted_idx,
                                                  const unsigned* __restrict__ base,
                                                  const unsigned* __restrict__ total,
                                                  unsigned short* __restrict__ Hg,
                                                  unsigned short* __restrict__ Lg) {
    const int w    = blockIdx.x * 4 + (threadIdx.x >> 6);
    const int lane = threadIdx.x & 63;
    const float4* pr = (const float4*)(prototypes + (size_t)w * FEAT);
    float4 p0 = pr[lane], p1 = pr[lane + 64], p2 = pr[lane + 128], p3 = pr[lane + 192];

    const int cnt = (int)total[w];
    const int bs  = (int)base[w];
    int myidx = (lane < cnt) ? sorted_idx[bs + lane] : 0;   // whole chain in one load (cnt<=64 w.h.p.)

    #define GETIDX(K) (((K) < cnt) ? (((K) < 64) ? __shfl(myidx, (K), 64) : sorted_idx[bs + (K)]) : 0)
    #define LOADROW(X0,X1,X2,X3, IDX) { \
        const float4* f_ = (const float4*)(features + (size_t)(IDX) * FEAT); \
        X0 = f_[lane]; X1 = f_[lane + 64]; X2 = f_[lane + 128]; X3 = f_[lane + 192]; }

    float4 a0,a1,a2,a3, b0,b1,b2,b3, c0,c1,c2,c3, d0,d1,d2,d3, e0,e1,e2,e3, g0,g1,g2,g3;
    LOADROW(a0,a1,a2,a3, GETIDX(0))
    LOADROW(b0,b1,b2,b3, GETIDX(1))
    LOADROW(c0,c1,c2,c3, GETIDX(2))
    LOADROW(d0,d1,d2,d3, GETIDX(3))
    LOADROW(e0,e1,e2,e3, GETIDX(4))
    LOADROW(g0,g1,g2,g3, GETIDX(5))

    #define STEP(X0,X1,X2,X3) \
        ema_step(p0,p1,p2,p3, X0,X1,X2,X3, features, GETIDX(k + 6), lane); ++k;

    int k = 0;
    while (k + 6 <= cnt) {
        STEP(a0,a1,a2,a3)
        STEP(b0,b1,b2,b3)
        STEP(c0,c1,c2,c3)
        STEP(d0,d1,d2,d3)
        STEP(e0,e1,e2,e3)
        STEP(g0,g1,g2,g3)
    }
    if (k < cnt) { STEP(a0,a1,a2,a3) }
    if (k < cnt) { STEP(b0,b1,b2,b3) }
    if (k < cnt) { STEP(c0,c1,c2,c3) }
    if (k < cnt) { STEP(d0,d1,d2,d3) }
    if (k < cnt) { STEP(e0,e1,e2,e3) }
    #undef STEP
    #undef LOADROW
    #undef GETIDX

    const size_t rb = (size_t)w * FEAT;
    write_hl(Hg, Lg, rb +       4 * lane, p0);
    write_hl(Hg, Lg, rb + 256 + 4 * lane, p1);
    write_hl(Hg, Lg, rb + 512 + 4 * lane, p2);
    write_hl(Hg, Lg, rb + 768 + 4 * lane, p3);
}

// ---------------- MFMA gram: C = H·H^T + L·H^T + H·L^T, fused exp row-sums + loss ----------------
__global__ __launch_bounds__(256) void gram_kernel(const unsigned short* __restrict__ Hg,
                                                   const unsigned short* __restrict__ Lg,
                                                   float* __restrict__ S,
                                                   unsigned* __restrict__ counter,
                                                   float* __restrict__ out) {
    __shared__ short Hms[64 * LPITCH];
    __shared__ short Lms[64 * LPITCH];
    __shared__ short Hns[64 * LPITCH];
    __shared__ short Lns[64 * LPITCH];
    const int t = threadIdx.x;
    const int l = t & 63, wid = t >> 6;
    const int wr = wid >> 1, wc = wid & 1;
    const int m0 = blockIdx.y * 64, n0 = blockIdx.x * 64;
    const int lg = l >> 4, lc = l & 15;

    const short* Hp = (const short*)Hg;
    const short* Lp = (const short*)Lg;

    f32x4 acc[2][2] = {};

    const int r0 = t >> 3,           c0 = t & 7;            // staging unit t
    const int r1 = (t + 256) >> 3,   c1 = t & 7;            // staging unit t+256

    for (int k0 = 0; k0 < FEAT; k0 += 64) {
        short8 hm0 = *(const short8*)(Hp + (size_t)(m0 + r0) * FEAT + k0 + c0 * 8);
        short8 hm1 = *(const short8*)(Hp + (size_t)(m0 + r1) * FEAT + k0 + c1 * 8);
        short8 lm0 = *(const short8*)(Lp + (size_t)(m0 + r0) * FEAT + k0 + c0 * 8);
        short8 lm1 = *(const short8*)(Lp + (size_t)(m0 + r1) * FEAT + k0 + c1 * 8);
        short8 hn0 = *(const short8*)(Hp + (size_t)(n0 + r0) * FEAT + k0 + c0 * 8);
        short8 hn1 = *(const short8*)(Hp + (size_t)(n0 + r1) * FEAT + k0 + c1 * 8);
        short8 ln0 = *(const short8*)(Lp + (size_t)(n0 + r0) * FEAT + k0 + c0 * 8);
        short8 ln1 = *(const short8*)(Lp + (size_t)(n0 + r1) * FEAT + k0 + c1 * 8);
        __syncthreads();                       // previous compute done before overwrite
        *(short8*)(Hms + r0 * LPITCH + c0 * 8) = hm0;
        *(short8*)(Hms + r1 * LPITCH + c1 * 8) = hm1;
        *(short8*)(Lms + r0 * LPITCH + c0 * 8) = lm0;
        *(short8*)(Lms + r1 * LPITCH + c1 * 8) = lm1;
        *(short8*)(Hns + r0 * LPITCH + c0 * 8) = hn0;
        *(short8*)(Hns + r1 * LPITCH + c1 * 8) = hn1;
        *(short8*)(Lns + r0 * LPITCH + c0 * 8) = ln0;
        *(short8*)(Lns + r1 * LPITCH + c1 * 8) = ln1;
        __syncthreads();
        #pragma unroll
        for (int kk = 0; kk < 2; ++kk) {
            short8 ah[2], al[2], bh[2], bl[2];
            #pragma unroll
            for (int mi = 0; mi < 2; ++mi) {
                ah[mi] = *(const short8*)(Hms + (wr * 32 + mi * 16 + lc) * LPITCH + kk * 32 + lg * 8);
                al[mi] = *(const short8*)(Lms + (wr * 32 + mi * 16 + lc) * LPITCH + kk * 32 + lg * 8);
            }
            #pragma unroll
            for (int ni = 0; ni < 2; ++ni) {
                bh[ni] = *(const short8*)(Hns + (wc * 32 + ni * 16 + lc) * LPITCH + kk * 32 + lg * 8);
                bl[ni] = *(const short8*)(Lns + (wc * 32 + ni * 16 + lc) * LPITCH + kk * 32 + lg * 8);
            }
            #pragma unroll
            for (int mi = 0; mi < 2; ++mi)
                #pragma unroll
                for (int ni = 0; ni < 2; ++ni) {
                    acc[mi][ni] = __builtin_amdgcn_mfma_f32_16x16x32_bf16(ah[mi], bh[ni], acc[mi][ni], 0, 0, 0);
                    acc[mi][ni] = __builtin_amdgcn_mfma_f32_16x16x32_bf16(al[mi], bh[ni], acc[mi][ni], 0, 0, 0);
                    acc[mi][ni] = __builtin_amdgcn_mfma_f32_16x16x32_bf16(ah[mi], bl[ni], acc[mi][ni], 0, 0, 0);
                }
        }
    }

    // epilogue: exp(10*logit) row sums, diagonal & out-of-range excluded
    #pragma unroll
    for (int mi = 0; mi < 2; ++mi) {
        #pragma unroll
        for (int j = 0; j < 4; ++j) {
            const int gr = m0 + wr * 32 + mi * 16 + lg * 4 + j;
            float s = 0.f;
            #pragma unroll
            for (int ni = 0; ni < 2; ++ni) {
                const int gc = n0 + wc * 32 + ni * 16 + lc;
                if (gr < N_CLS && gc < N_CLS && gr != gc) s += expf(acc[mi][ni][j] * 10.0f);
            }
            #pragma unroll
            for (int m = 1; m < 16; m <<= 1) s += __shfl_xor(s, m, 64);
            if (lc == 0 && gr < N_CLS) atomicAdd(&S[gr], s);
        }
    }

    // fused loss: last block reduces S
    __threadfence();
    __shared__ int amlast;
    if (t == 0) {
        unsigned old = __hip_atomic_fetch_add(&counter[0], 1u, __ATOMIC_ACQ_REL, __HIP_MEMORY_SCOPE_AGENT);
        amlast = (old == GRAM_BLOCKS - 1) ? 1 : 0;
    }
    __syncthreads();
    if (amlast) {
        float a = 0.f;
        for (int i = t; i < N_CLS; i += 256) {
            float sv = __hip_atomic_load(&S[i], __ATOMIC_RELAXED, __HIP_MEMORY_SCOPE_AGENT);
            a += logf(sv);
        }
        #pragma unroll
        for (int o = 32; o; o >>= 1) a += __shfl_xor(a, o, 64);
        __shared__ float red[4];
        if (l == 0) red[wid] = a;
        __syncthreads();
        if (t == 0) {
            float tot = red[0] + red[1] + red[2] + red[3];
            out[0] = tot / (float)N_CLS - logf(999.0f);   // TEMP/BASE_TEMP == 1.0
        }
    }
}

extern "C" void kernel_launch(void* const* d_in, const int* in_sizes, int n_in,
                              void* d_out, int out_size, void* d_ws, size_t ws_size,
                              hipStream_t stream) {
    const float* features   = (const float*)d_in[0];
    const float* prototypes = (const float*)d_in[1];
    const int*   labels     = (const int*)d_in[2];
    float* out = (float*)d_out;

    char* ws = (char*)d_ws;
    unsigned*       hist    = (unsigned*)(ws);                 // 1000*128*4 = 512000
    unsigned*       base    = (unsigned*)(ws + 0x80000);       // 4 KB
    unsigned*       total   = (unsigned*)(ws + 0x81000);       // 4 KB
    int*            sorted  = (int*)     (ws + 0x82000);       // 131072
    float*          S       = (float*)   (ws + 0xA4000);       // 4 KB
    unsigned*       counter = (unsigned*)(ws + 0xA5000);       // 8 B: [0]=gram, [1]=scan
    unsigned short* Hg      = (unsigned short*)(ws + 0x100000);// 1024*1024*2 = 2 MB
    unsigned short* Lg      = (unsigned short*)(ws + 0x300000);// 2 MB

    hist_kernel   <<<NBLK_H, 256, 0, stream>>>(labels, hist, S, counter);
    scan_kernel   <<<SCAN_BLOCKS, 256, 0, stream>>>(hist, total, base, counter);
    scatter_kernel<<<NBLK_H, 256, 0, stream>>>(labels, hist, base, sorted);
    ema_kernel    <<<SCAN_BLOCKS, 256, 0, stream>>>(features, prototypes, sorted, base, total, Hg, Lg);
    gram_kernel   <<<dim3(16, 16), 256, 0, stream>>>(Hg, Lg, S, counter, out);
}